// Round 10
// baseline (20.669 us; speedup 1.0000x reference)
//
#include <hip/hip_runtime.h>
#include <hip/hip_bf16.h>

typedef short short8 __attribute__((ext_vector_type(8)));
typedef float f32x4 __attribute__((ext_vector_type(4)));

union FragAB { unsigned long long l[2]; int i[4]; short8 v; };

// Round-10: wave-interleaved j-groups for a time-uniform store stream.
//
// Swapped-operand formulation: D[p=(b,f), j] = sum_i A[p,i] * B[i,j]
//   A[p,i] = bf16(x[b, sx, i, f])            (Xts rows, k-contiguous)
//   B[i,j] = T[j,i] = wfor[255 + diag - j + i]
//   wfor[q] = krow[q] for q in [0,255], 0 elsewhere (zero-pad = triangular
//   mask AND the diagonal roll-by-one, which switches divisor to j+1-diag).
// Four shifted copies of wfor (copy s holds wfor shifted +s) make every
// lane's 8-element window 8-byte aligned -> B-frag = 2x ds_read_b64.
//
// Block = (hy, sx, nt) = 64p x 256j tile. Wave w owns the four 16-wide
// j-groups at wj0_g = 16w + 64g (g=0..3). Group g needs k in [0, wj0_g+16)
// -> completes at K-step ~2g+1; its stores issue immediately -> each wave
// emits a 4-store burst every ~2 K-steps instead of 16 stores at loop end.
// A-frags are read ONCE per kc and shared by all active groups (the fix for
// round-8's regression). Per-wave trips 7/7/8/8 -> waves finish together.
// MFMA 288/block (triangle-tight; dropped steps were provably all-zero).
// lb(256,4): 4 blocks/CU (LDS 150 KB), grid 1024 = exactly 1 generation.
__global__ __launch_bounds__(256, 4)
void k_fused(const float* __restrict__ x,     // [16,8,256,16]
             const float* __restrict__ kern,  // [4,8,8,256]
             float* __restrict__ out)         // [16,4,8,8,256,16]
{
    __shared__ __align__(16) ushort Xts[64 * 264];   // [p][k], row 528 B
    __shared__ __align__(8)  ushort wforL[4][336];   // [shift][q]
    __shared__ float rtab[256];

    const int blk = blockIdx.x;             // 0..1023
    const int hy = blk & 31;                // h*8 + sy
    const int sx = (blk >> 5) & 7;
    const int nt = blk >> 8;                // p-quarter (b-quad)
    const int h = hy >> 3, sy = hy & 7;
    const int diag = (sx == sy) ? 1 : 0;
    const int t = threadIdx.x;

    // ---- wfor shift-copies (bf16) ----
    {
        const float* krow = kern + ((h * 8 + sx) * 8 + sy) * 256;
        #pragma unroll
        for (int s = 0; s < 4; ++s) {
            #pragma unroll
            for (int pass = 0; pass < 2; ++pass) {
                int q = t + pass * 256;
                if (q < 336) {
                    int src = q - s;
                    float v = (src >= 0 && src < 256) ? krow[src] : 0.0f;
                    __hip_bfloat16 hv = __float2bfloat16(v);
                    wforL[s][q] = reinterpret_cast<ushort&>(hv);
                }
            }
        }
    }
    // ---- reciprocal table for this block's diag ----
    {
        int denom = t + 1 - diag;
        rtab[t] = (denom > 0) ? (1.0f / (float)denom) : 0.0f;
    }
    // ---- stage + transpose x quarter-slice -> Xts: Xts[bl*16+f][k] ----
    {
        const float4* xbase = reinterpret_cast<const float4*>(x);
        #pragma unroll
        for (int it = 0; it < 8; ++it) {
            int id = it * 256 + t;              // 0..2047
            int fq = id & 3;
            int k2 = (id >> 2) & 127;
            int bl = id >> 9;                   // local b 0..3
            const float4* rowp = xbase + ((size_t)((nt * 4 + bl) * 8 + sx)) * 1024;
            float4 a = rowp[(2 * k2) * 4 + fq];
            float4 cq = rowp[(2 * k2 + 1) * 4 + fq];
            #pragma unroll
            for (int e = 0; e < 4; ++e) {
                float va = (&a.x)[e], vb = (&cq.x)[e];
                __hip_bfloat16 ha = __float2bfloat16(va);
                __hip_bfloat16 hb = __float2bfloat16(vb);
                uint u = (uint)reinterpret_cast<ushort&>(ha) |
                         ((uint)reinterpret_cast<ushort&>(hb) << 16);
                int row = bl * 16 + fq * 4 + e;
                *reinterpret_cast<uint*>(reinterpret_cast<char*>(Xts) + row * 528 + k2 * 4) = u;
            }
        }
    }
    __syncthreads();

    const int lane = t & 63, wid = t >> 6;
    const int laneM = lane & 15, laneG = lane >> 4;
    const int wb = wid * 16;                    // wave's j-group base

    const char* XtsB = reinterpret_cast<const char*>(Xts);
    const char* WB = reinterpret_cast<const char*>(wforL);
    const int abyte = laneM * 528 + laneG * 16;

    // Group g: j = wb + 64g + laneM. B element e at step kc reads
    // wfor[w00g + kc + e], w00g = 255 + diag - (wb+64g) - laneM + 8*laneG.
    const int w000 = 255 + diag - wb - laneM + 8 * laneG;   // g = 0
    const int s = (laneM - diag + 1) & 3;       // makes (w000+s) % 4 == 0
    const int bB0 = s * 674 + 2 * w000;         // byte base for g=0 (incl. +s)

    f32x4 acc[4][4];                            // [g][m]
    #pragma unroll
    for (int g = 0; g < 4; ++g)
        #pragma unroll
        for (int m = 0; m < 4; ++m)
            acc[g][m] = (f32x4){0.0f, 0.0f, 0.0f, 0.0f};

    const int kend = wb + 208;                  // group-3 bound: wb+192+16
    for (int kc = 0; kc < kend; kc += 32) {
        FragAB af[4];
        #pragma unroll
        for (int m = 0; m < 4; ++m) {
            const int4 raw = *reinterpret_cast<const int4*>(XtsB + abyte + m * 8448 + kc * 2);
            af[m].i[0] = raw.x; af[m].i[1] = raw.y;
            af[m].i[2] = raw.z; af[m].i[3] = raw.w;
        }
        #pragma unroll
        for (int g = 0; g < 4; ++g) {
            const int kmaxg = wb + 64 * g + 16; // wave-uniform bound
            if (kc < kmaxg) {
                FragAB bf;
                {
                    const char* p = WB + (bB0 - 128 * g) + kc * 2;
                    bf.l[0] = *reinterpret_cast<const unsigned long long*>(p);
                    bf.l[1] = *reinterpret_cast<const unsigned long long*>(p + 8);
                }
                #pragma unroll
                for (int m = 0; m < 4; ++m)
                    acc[g][m] = __builtin_amdgcn_mfma_f32_16x16x32_bf16(
                        af[m].v, bf.v, acc[g][m], 0, 0, 0);
                if (kc + 32 >= kmaxg) {
                    // group g complete -> store now (spreads write stream)
                    const int j = wb + 64 * g + laneM;
                    const float rt = rtab[j];
                    #pragma unroll
                    for (int m = 0; m < 4; ++m) {
                        const int b_ = nt * 4 + m;
                        float* dst = out
                            + (((size_t)(b_ * 4 + h) * 8 + sx) * 8 + sy) * 4096
                            + (size_t)j * 16 + laneG * 4;
                        f32x4 v = acc[g][m] * rt;
                        __builtin_nontemporal_store(v, reinterpret_cast<f32x4*>(dst));
                    }
                }
            }
        }
    }
}

extern "C" void kernel_launch(void* const* d_in, const int* in_sizes, int n_in,
                              void* d_out, int out_size, void* d_ws, size_t ws_size,
                              hipStream_t stream) {
    const float* x    = (const float*)d_in[0];   // [16,8,256,16]
    const float* kern = (const float*)d_in[1];   // [4,8,8,256]
    float* out = (float*)d_out;                  // [16,4,8,8,256,16]

    k_fused<<<1024, 256, 0, stream>>>(x, kern, out);
}